// Round 3
// baseline (990.540 us; speedup 1.0000x reference)
//
#include <hip/hip_runtime.h>

#define D 64
#define EPSV 1e-5f

// ---------------- preprocessing ----------------

__global__ void k_init(int* deg, int* cursor, int n) {
    int i = blockIdx.x * blockDim.x + threadIdx.x;
    if (i < n) { deg[i] = 1; cursor[i] = 0; }   // 1 = self-loop
}

__global__ void k_count(const int* __restrict__ dst, int* __restrict__ deg, int e) {
    int i = blockIdx.x * blockDim.x + threadIdx.x;
    if (i < e) atomicAdd(&deg[dst[i]], 1);
}

// inclusive scan of deg in 256-chunks
__global__ void k_scan_block(const int* __restrict__ deg, int* __restrict__ incl,
                             int* __restrict__ bsums, int n) {
    __shared__ int s[256];
    int i = blockIdx.x * 256 + threadIdx.x;
    int v = (i < n) ? deg[i] : 0;
    s[threadIdx.x] = v;
    __syncthreads();
    for (int off = 1; off < 256; off <<= 1) {
        int t = (threadIdx.x >= off) ? s[threadIdx.x - off] : 0;
        __syncthreads();
        s[threadIdx.x] += t;
        __syncthreads();
    }
    if (i < n) incl[i] = s[threadIdx.x];
    if (threadIdx.x == 255) bsums[blockIdx.x] = s[255];
}

// single-block exclusive scan of the block sums (nb <= 1024)
__global__ void k_scan_sums(int* bsums, int nb) {
    __shared__ int s[1024];
    int t = threadIdx.x;
    int orig = (t < nb) ? bsums[t] : 0;
    s[t] = orig;
    __syncthreads();
    for (int off = 1; off < 1024; off <<= 1) {
        int v = (t >= off) ? s[t - off] : 0;
        __syncthreads();
        s[t] += v;
        __syncthreads();
    }
    if (t < nb) bsums[t] = s[t] - orig;  // exclusive prefix
}

__global__ void k_finalize(const int* __restrict__ incl, const int* __restrict__ deg,
                           const int* __restrict__ bsums, int* __restrict__ row_ptr,
                           float* __restrict__ dis, int n, int total) {
    int i = blockIdx.x * blockDim.x + threadIdx.x;
    if (i < n) {
        row_ptr[i] = incl[i] - deg[i] + bsums[i >> 8];   // exclusive scan
        dis[i] = rsqrtf((float)deg[i]);                  // deg >= 1 always
    }
    if (i == 0) row_ptr[n] = total;
}

// CSR fill with interleaved payload: edge[j] = {src, bitcast(dis[src])}
// (dis is ready: k_finalize ran before). Kills the dependent dis-gather
// and the shfl-broadcast hop in the hot kernel.
__global__ void k_fill(const int* __restrict__ src, const int* __restrict__ dst,
                       const int* __restrict__ row_ptr, int* __restrict__ cursor,
                       const float* __restrict__ dis, int2* __restrict__ edge,
                       int e, int n) {
    int i = blockIdx.x * blockDim.x + threadIdx.x;
    int tot = e + n;
    if (i >= tot) return;
    int s_, d_;
    if (i < e) { s_ = src[i]; d_ = dst[i]; }
    else       { s_ = d_ = i - e; }          // self-loop
    int p = atomicAdd(&cursor[d_], 1);
    edge[row_ptr[d_] + p] = make_int2(s_, __float_as_int(dis[s_]));
}

// Wt[c][k] = W[k][c] so lane c can load its W-column contiguously (16 float4s)
__global__ void k_transpose(const float* __restrict__ W, float* __restrict__ Wt) {
    for (int i = threadIdx.x; i < D * D; i += blockDim.x) {
        int k = i >> 6, c = i & 63;
        Wt[c * D + k] = W[k * D + c];
    }
}

// ---------------- fused per-round kernel ----------------
// One wave per node. lane = feature. agg = (sum_u dis_u * x[u]) * dis_w @ W + b,
// then in-register LayerNorm. Edge chain: broadcast 8B payload -> x row -> FMA.
__global__ __launch_bounds__(256, 4) void k_round(
    const float* __restrict__ x, const int* __restrict__ row_ptr,
    const int2* __restrict__ edge, const float* __restrict__ dis,
    const float* __restrict__ Wt, const float* __restrict__ b,
    const float* __restrict__ gamma, const float* __restrict__ beta,
    float* __restrict__ out, int n) {
    const int lane = threadIdx.x & 63;
    const int w = blockIdx.x * 4 + (threadIdx.x >> 6);
    if (w >= n) return;

    const int jb = row_ptr[w], je = row_ptr[w + 1];
    float acc = 0.f;
    int j = jb;
    // 8-wide batches: 8 payload broadcast-loads in flight, then 8 independent
    // x-row loads in flight, then 8 FMAs.
    for (; j + 8 <= je; j += 8) {
        int2 e0 = edge[j + 0], e1 = edge[j + 1], e2 = edge[j + 2], e3 = edge[j + 3];
        int2 e4 = edge[j + 4], e5 = edge[j + 5], e6 = edge[j + 6], e7 = edge[j + 7];
        float x0 = x[(size_t)e0.x * D + lane];
        float x1 = x[(size_t)e1.x * D + lane];
        float x2 = x[(size_t)e2.x * D + lane];
        float x3 = x[(size_t)e3.x * D + lane];
        float x4 = x[(size_t)e4.x * D + lane];
        float x5 = x[(size_t)e5.x * D + lane];
        float x6 = x[(size_t)e6.x * D + lane];
        float x7 = x[(size_t)e7.x * D + lane];
        acc += __int_as_float(e0.y) * x0; acc += __int_as_float(e1.y) * x1;
        acc += __int_as_float(e2.y) * x2; acc += __int_as_float(e3.y) * x3;
        acc += __int_as_float(e4.y) * x4; acc += __int_as_float(e5.y) * x5;
        acc += __int_as_float(e6.y) * x6; acc += __int_as_float(e7.y) * x7;
    }
    if (j + 4 <= je) {
        int2 e0 = edge[j + 0], e1 = edge[j + 1], e2 = edge[j + 2], e3 = edge[j + 3];
        float x0 = x[(size_t)e0.x * D + lane];
        float x1 = x[(size_t)e1.x * D + lane];
        float x2 = x[(size_t)e2.x * D + lane];
        float x3 = x[(size_t)e3.x * D + lane];
        acc += __int_as_float(e0.y) * x0; acc += __int_as_float(e1.y) * x1;
        acc += __int_as_float(e2.y) * x2; acc += __int_as_float(e3.y) * x3;
        j += 4;
    }
    for (; j < je; ++j) {
        int2 e = edge[j];
        acc += __int_as_float(e.y) * x[(size_t)e.x * D + lane];
    }
    acc *= dis[w];

    // W column for this lane, loaded AFTER the gather (lower live range overlap)
    float4 wt[16];
    const float4* wrow = (const float4*)(Wt + (size_t)lane * D);
#pragma unroll
    for (int k = 0; k < 16; ++k) wt[k] = wrow[k];

    // y[lane] = sum_k acc[k] * W[k][lane] + b[lane]
    float y = b[lane];
#pragma unroll
    for (int k = 0; k < 16; ++k) {
        float a0 = __shfl(acc, 4 * k),     a1 = __shfl(acc, 4 * k + 1);
        float a2 = __shfl(acc, 4 * k + 2), a3 = __shfl(acc, 4 * k + 3);
        y += a0 * wt[k].x; y += a1 * wt[k].y;
        y += a2 * wt[k].z; y += a3 * wt[k].w;
    }

    // LayerNorm across the 64 lanes
    float s = y;
#pragma unroll
    for (int msk = 1; msk < 64; msk <<= 1) s += __shfl_xor(s, msk, 64);
    float mu = s * (1.0f / 64.0f);
    float dif = y - mu;
    float q = dif * dif;
#pragma unroll
    for (int msk = 1; msk < 64; msk <<= 1) q += __shfl_xor(q, msk, 64);
    float rstd = rsqrtf(q * (1.0f / 64.0f) + EPSV);
    out[(size_t)w * D + lane] = dif * rstd * gamma[lane] + beta[lane];
}

// ---------------- launch ----------------

extern "C" void kernel_launch(void* const* d_in, const int* in_sizes, int n_in,
                              void* d_out, int out_size, void* d_ws, size_t ws_size,
                              hipStream_t stream) {
    const float* x0    = (const float*)d_in[0];
    const int*   ei    = (const int*)d_in[1];
    const float* W     = (const float*)d_in[2];
    const float* b     = (const float*)d_in[3];
    const float* gamma = (const float*)d_in[4];
    const float* beta  = (const float*)d_in[5];

    const int N = in_sizes[0] / D;
    const int E = in_sizes[1] / 2;
    const int* src = ei;
    const int* dst = ei + E;

    char* ws = (char*)d_ws;
    size_t off = 0;
    auto alloc = [&](size_t bytes) {
        off = (off + 255) & ~(size_t)255;
        void* p = ws + off;
        off += bytes;
        return p;
    };
    int*   deg     = (int*)alloc((size_t)N * 4);
    int*   cursor  = (int*)alloc((size_t)N * 4);
    int*   incl    = (int*)alloc((size_t)N * 4);
    int*   bsums   = (int*)alloc(4096);
    int*   row_ptr = (int*)alloc((size_t)(N + 1) * 4);
    float* dis     = (float*)alloc((size_t)N * 4);
    int2*  edge    = (int2*)alloc((size_t)(E + N) * 8);
    float* Wt      = (float*)alloc((size_t)D * D * 4);
    float* t       = (float*)alloc((size_t)N * D * 4);
    (void)ws_size;

    const int nbN  = (N + 255) / 256;
    const int nbE  = (E + 255) / 256;
    const int nbEN = (E + N + 255) / 256;

    k_init<<<nbN, 256, 0, stream>>>(deg, cursor, N);
    k_count<<<nbE, 256, 0, stream>>>(dst, deg, E);
    k_scan_block<<<nbN, 256, 0, stream>>>(deg, incl, bsums, N);
    k_scan_sums<<<1, 1024, 0, stream>>>(bsums, nbN);
    k_finalize<<<nbN, 256, 0, stream>>>(incl, deg, bsums, row_ptr, dis, N, E + N);
    k_fill<<<nbEN, 256, 0, stream>>>(src, dst, row_ptr, cursor, dis, edge, E, N);
    k_transpose<<<1, 256, 0, stream>>>(W, Wt);

    float* out = (float*)d_out;
    const int GRID = (N + 3) / 4;          // one wave per node
    // ping-pong: x0 -> t -> out -> t -> out
    k_round<<<GRID, 256, 0, stream>>>(x0,  row_ptr, edge, dis, Wt, b, gamma, beta, t,   N);
    k_round<<<GRID, 256, 0, stream>>>(t,   row_ptr, edge, dis, Wt, b, gamma, beta, out, N);
    k_round<<<GRID, 256, 0, stream>>>(out, row_ptr, edge, dis, Wt, b, gamma, beta, t,   N);
    k_round<<<GRID, 256, 0, stream>>>(t,   row_ptr, edge, dis, Wt, b, gamma, beta, out, N);
}

// Round 4
// 683.829 us; speedup vs baseline: 1.4485x; 1.4485x over previous
//
#include <hip/hip_runtime.h>

#define D 64
#define EPSV 1e-5f

// ---------------- preprocessing ----------------

__global__ void k_init(int* deg, int* cursor, int n) {
    int i = blockIdx.x * blockDim.x + threadIdx.x;
    if (i < n) { deg[i] = 1; cursor[i] = 0; }   // 1 = self-loop
}

__global__ void k_count(const int* __restrict__ dst, int* __restrict__ deg, int e) {
    int i = blockIdx.x * blockDim.x + threadIdx.x;
    if (i < e) atomicAdd(&deg[dst[i]], 1);
}

// inclusive scan of deg in 256-chunks
__global__ void k_scan_block(const int* __restrict__ deg, int* __restrict__ incl,
                             int* __restrict__ bsums, int n) {
    __shared__ int s[256];
    int i = blockIdx.x * 256 + threadIdx.x;
    int v = (i < n) ? deg[i] : 0;
    s[threadIdx.x] = v;
    __syncthreads();
    for (int off = 1; off < 256; off <<= 1) {
        int t = (threadIdx.x >= off) ? s[threadIdx.x - off] : 0;
        __syncthreads();
        s[threadIdx.x] += t;
        __syncthreads();
    }
    if (i < n) incl[i] = s[threadIdx.x];
    if (threadIdx.x == 255) bsums[blockIdx.x] = s[255];
}

// single-block exclusive scan of the block sums (nb <= 1024)
__global__ void k_scan_sums(int* bsums, int nb) {
    __shared__ int s[1024];
    int t = threadIdx.x;
    int orig = (t < nb) ? bsums[t] : 0;
    s[t] = orig;
    __syncthreads();
    for (int off = 1; off < 1024; off <<= 1) {
        int v = (t >= off) ? s[t - off] : 0;
        __syncthreads();
        s[t] += v;
        __syncthreads();
    }
    if (t < nb) bsums[t] = s[t] - orig;  // exclusive prefix
}

__global__ void k_finalize(const int* __restrict__ incl, const int* __restrict__ deg,
                           const int* __restrict__ bsums, int* __restrict__ row_ptr,
                           float* __restrict__ dis, int n, int total) {
    int i = blockIdx.x * blockDim.x + threadIdx.x;
    if (i < n) {
        row_ptr[i] = incl[i] - deg[i] + bsums[i >> 8];   // exclusive scan
        dis[i] = rsqrtf((float)deg[i]);                  // deg >= 1 always
    }
    if (i == 0) row_ptr[n] = total;
}

// CSR fill with interleaved payload: edge[j] = {src, bitcast(dis[src])}
__global__ void k_fill(const int* __restrict__ src, const int* __restrict__ dst,
                       const int* __restrict__ row_ptr, int* __restrict__ cursor,
                       const float* __restrict__ dis, int2* __restrict__ edge,
                       int e, int n) {
    int i = blockIdx.x * blockDim.x + threadIdx.x;
    int tot = e + n;
    if (i >= tot) return;
    int s_, d_;
    if (i < e) { s_ = src[i]; d_ = dst[i]; }
    else       { s_ = d_ = i - e; }          // self-loop
    int p = atomicAdd(&cursor[d_], 1);
    edge[row_ptr[d_] + p] = make_int2(s_, __float_as_int(dis[s_]));
}

// Wt[c][k] = W[k][c] so lane c can load its W-column contiguously (16 float4s)
__global__ void k_transpose(const float* __restrict__ W, float* __restrict__ Wt) {
    for (int i = threadIdx.x; i < D * D; i += blockDim.x) {
        int k = i >> 6, c = i & 63;
        Wt[c * D + k] = W[k * D + c];
    }
}

// ---------------- fused per-round kernel ----------------
// Grid-strided, one wave per node at a time. Gather phase: quarter q
// (lanes 16q..16q+15) owns edge slot q; each lane loads a float4 (16 B)
// covering features 4*(lane&15)..+3 of that edge's x-row -> 4 edges per
// vector-load instruction instead of 1. Cross-quarter shfl_xor reduction
// restores lane-group=feature layout, then shfl-GEMM + in-register LN.
// NOTE: no min-occupancy hint — (256,4) at round 3 made the compiler
// register-starve (VGPR=32) and serialize the gather ILP.
__global__ __launch_bounds__(256) void k_round(
    const float* __restrict__ x, const int* __restrict__ row_ptr,
    const int2* __restrict__ edge, const float* __restrict__ dis,
    const float* __restrict__ Wt, const float* __restrict__ b,
    const float* __restrict__ gamma, const float* __restrict__ beta,
    float* __restrict__ out, int n, int nwaves) {
    const int lane = threadIdx.x & 63;
    const int q    = lane >> 4;       // edge slot within a 4-edge group
    const int fl   = lane & 15;       // float4 index within the 64-float row

    // W column for this lane (c = lane), loaded once per wave
    float4 wt[16];
    const float4* wrow = (const float4*)(Wt + (size_t)lane * D);
#pragma unroll
    for (int k = 0; k < 16; ++k) wt[k] = wrow[k];
    const float bl = b[lane], gl = gamma[lane], be = beta[lane];

    const int w0 = blockIdx.x * 4 + (threadIdx.x >> 6);
    for (int w = w0; w < n; w += nwaves) {
        const int jb = row_ptr[w], je = row_ptr[w + 1];
        float4 acc = make_float4(0.f, 0.f, 0.f, 0.f);
        int j = jb;
        // 8 edges per iter: two independent 16B-per-lane row loads in flight
        for (; j + 8 <= je; j += 8) {
            int2 ea = edge[j + q];
            int2 eb = edge[j + 4 + q];
            float4 va = ((const float4*)(x + (size_t)ea.x * D))[fl];
            float4 vb = ((const float4*)(x + (size_t)eb.x * D))[fl];
            float wa = __int_as_float(ea.y), wb = __int_as_float(eb.y);
            acc.x += wa * va.x; acc.y += wa * va.y;
            acc.z += wa * va.z; acc.w += wa * va.w;
            acc.x += wb * vb.x; acc.y += wb * vb.y;
            acc.z += wb * vb.z; acc.w += wb * vb.w;
        }
        if (j + 4 <= je) {
            int2 ea = edge[j + q];
            float4 va = ((const float4*)(x + (size_t)ea.x * D))[fl];
            float wa = __int_as_float(ea.y);
            acc.x += wa * va.x; acc.y += wa * va.y;
            acc.z += wa * va.z; acc.w += wa * va.w;
            j += 4;
        }
        if (j < je) {                     // 1..3 leftover edges, clamp + zero-weight
            int m = je - j;
            int2 ea = edge[j + (q < m ? q : 0)];
            float wa = (q < m) ? __int_as_float(ea.y) : 0.f;
            float4 va = ((const float4*)(x + (size_t)ea.x * D))[fl];
            acc.x += wa * va.x; acc.y += wa * va.y;
            acc.z += wa * va.z; acc.w += wa * va.w;
        }
        // reduce partial sums across the 4 quarters
        acc.x += __shfl_xor(acc.x, 16); acc.y += __shfl_xor(acc.y, 16);
        acc.z += __shfl_xor(acc.z, 16); acc.w += __shfl_xor(acc.w, 16);
        acc.x += __shfl_xor(acc.x, 32); acc.y += __shfl_xor(acc.y, 32);
        acc.z += __shfl_xor(acc.z, 32); acc.w += __shfl_xor(acc.w, 32);
        const float dv = dis[w];
        acc.x *= dv; acc.y *= dv; acc.z *= dv; acc.w *= dv;

        // y[lane] = sum_k agg[k] * W[k][lane] + b[lane]
        // lane g (g<16) holds agg[4g..4g+3] (replicated across quarters)
        float y = bl;
#pragma unroll
        for (int g = 0; g < 16; ++g) {
            float a0 = __shfl(acc.x, g), a1 = __shfl(acc.y, g);
            float a2 = __shfl(acc.z, g), a3 = __shfl(acc.w, g);
            y += a0 * wt[g].x; y += a1 * wt[g].y;
            y += a2 * wt[g].z; y += a3 * wt[g].w;
        }

        // LayerNorm across the 64 lanes
        float s = y;
#pragma unroll
        for (int msk = 1; msk < 64; msk <<= 1) s += __shfl_xor(s, msk, 64);
        float mu = s * (1.0f / 64.0f);
        float dif = y - mu;
        float qv = dif * dif;
#pragma unroll
        for (int msk = 1; msk < 64; msk <<= 1) qv += __shfl_xor(qv, msk, 64);
        float rstd = rsqrtf(qv * (1.0f / 64.0f) + EPSV);
        out[(size_t)w * D + lane] = dif * rstd * gl + be;
    }
}

// ---------------- launch ----------------

extern "C" void kernel_launch(void* const* d_in, const int* in_sizes, int n_in,
                              void* d_out, int out_size, void* d_ws, size_t ws_size,
                              hipStream_t stream) {
    const float* x0    = (const float*)d_in[0];
    const int*   ei    = (const int*)d_in[1];
    const float* W     = (const float*)d_in[2];
    const float* b     = (const float*)d_in[3];
    const float* gamma = (const float*)d_in[4];
    const float* beta  = (const float*)d_in[5];

    const int N = in_sizes[0] / D;
    const int E = in_sizes[1] / 2;
    const int* src = ei;
    const int* dst = ei + E;

    char* ws = (char*)d_ws;
    size_t off = 0;
    auto alloc = [&](size_t bytes) {
        off = (off + 255) & ~(size_t)255;
        void* p = ws + off;
        off += bytes;
        return p;
    };
    int*   deg     = (int*)alloc((size_t)N * 4);
    int*   cursor  = (int*)alloc((size_t)N * 4);
    int*   incl    = (int*)alloc((size_t)N * 4);
    int*   bsums   = (int*)alloc(4096);
    int*   row_ptr = (int*)alloc((size_t)(N + 1) * 4);
    float* dis     = (float*)alloc((size_t)N * 4);
    int2*  edge    = (int2*)alloc((size_t)(E + N) * 8);
    float* Wt      = (float*)alloc((size_t)D * D * 4);
    float* t       = (float*)alloc((size_t)N * D * 4);
    (void)ws_size;

    const int nbN  = (N + 255) / 256;
    const int nbE  = (E + 255) / 256;
    const int nbEN = (E + N + 255) / 256;

    k_init<<<nbN, 256, 0, stream>>>(deg, cursor, N);
    k_count<<<nbE, 256, 0, stream>>>(dst, deg, E);
    k_scan_block<<<nbN, 256, 0, stream>>>(deg, incl, bsums, N);
    k_scan_sums<<<1, 1024, 0, stream>>>(bsums, nbN);
    k_finalize<<<nbN, 256, 0, stream>>>(incl, deg, bsums, row_ptr, dis, N, E + N);
    k_fill<<<nbEN, 256, 0, stream>>>(src, dst, row_ptr, cursor, dis, edge, E, N);
    k_transpose<<<1, 256, 0, stream>>>(W, Wt);

    float* out = (float*)d_out;
    const int GRID = 1536;                 // 6144 waves, ~16 nodes/wave
    const int NW   = GRID * 4;
    // ping-pong: x0 -> t -> out -> t -> out
    k_round<<<GRID, 256, 0, stream>>>(x0,  row_ptr, edge, dis, Wt, b, gamma, beta, t,   N, NW);
    k_round<<<GRID, 256, 0, stream>>>(t,   row_ptr, edge, dis, Wt, b, gamma, beta, out, N, NW);
    k_round<<<GRID, 256, 0, stream>>>(out, row_ptr, edge, dis, Wt, b, gamma, beta, t,   N, NW);
    k_round<<<GRID, 256, 0, stream>>>(t,   row_ptr, edge, dis, Wt, b, gamma, beta, out, N, NW);
}

// Round 5
// 587.608 us; speedup vs baseline: 1.6857x; 1.1638x over previous
//
#include <hip/hip_runtime.h>

#define D 64
#define EPSV 1e-5f

// ---------------- preprocessing ----------------

__global__ void k_init(int* deg, int* cursor, int n) {
    int i = blockIdx.x * blockDim.x + threadIdx.x;
    if (i < n) { deg[i] = 1; cursor[i] = 0; }   // 1 = self-loop
}

__global__ void k_count(const int* __restrict__ dst, int* __restrict__ deg, int e) {
    int i = blockIdx.x * blockDim.x + threadIdx.x;
    if (i < e) atomicAdd(&deg[dst[i]], 1);
}

// inclusive scan of deg in 256-chunks
__global__ void k_scan_block(const int* __restrict__ deg, int* __restrict__ incl,
                             int* __restrict__ bsums, int n) {
    __shared__ int s[256];
    int i = blockIdx.x * 256 + threadIdx.x;
    int v = (i < n) ? deg[i] : 0;
    s[threadIdx.x] = v;
    __syncthreads();
    for (int off = 1; off < 256; off <<= 1) {
        int t = (threadIdx.x >= off) ? s[threadIdx.x - off] : 0;
        __syncthreads();
        s[threadIdx.x] += t;
        __syncthreads();
    }
    if (i < n) incl[i] = s[threadIdx.x];
    if (threadIdx.x == 255) bsums[blockIdx.x] = s[255];
}

// single-block exclusive scan of the block sums (nb <= 1024)
__global__ void k_scan_sums(int* bsums, int nb) {
    __shared__ int s[1024];
    int t = threadIdx.x;
    int orig = (t < nb) ? bsums[t] : 0;
    s[t] = orig;
    __syncthreads();
    for (int off = 1; off < 1024; off <<= 1) {
        int v = (t >= off) ? s[t - off] : 0;
        __syncthreads();
        s[t] += v;
        __syncthreads();
    }
    if (t < nb) bsums[t] = s[t] - orig;  // exclusive prefix
}

__global__ void k_finalize(const int* __restrict__ incl, const int* __restrict__ deg,
                           const int* __restrict__ bsums, int* __restrict__ row_ptr,
                           float* __restrict__ dis, int n, int total) {
    int i = blockIdx.x * blockDim.x + threadIdx.x;
    if (i < n) {
        row_ptr[i] = incl[i] - deg[i] + bsums[i >> 8];   // exclusive scan
        dis[i] = rsqrtf((float)deg[i]);                  // deg >= 1 always
    }
    if (i == 0) row_ptr[n] = total;
}

// CSR fill with interleaved payload: edge[j] = {src, bitcast(dis[src])}
__global__ void k_fill(const int* __restrict__ src, const int* __restrict__ dst,
                       const int* __restrict__ row_ptr, int* __restrict__ cursor,
                       const float* __restrict__ dis, int2* __restrict__ edge,
                       int e, int n) {
    int i = blockIdx.x * blockDim.x + threadIdx.x;
    int tot = e + n;
    if (i >= tot) return;
    int s_, d_;
    if (i < e) { s_ = src[i]; d_ = dst[i]; }
    else       { s_ = d_ = i - e; }          // self-loop
    int p = atomicAdd(&cursor[d_], 1);
    edge[row_ptr[d_] + p] = make_int2(s_, __float_as_int(dis[s_]));
}

// Wt[c][k] = W[k][c] so lane c can load its W-column contiguously (16 float4s)
__global__ void k_transpose(const float* __restrict__ W, float* __restrict__ Wt) {
    for (int i = threadIdx.x; i < D * D; i += blockDim.x) {
        int k = i >> 6, c = i & 63;
        Wt[c * D + k] = W[k * D + c];
    }
}

// ---------------- round kernel 1: dense transform h = x @ W ----------------
// lane = output column. W column pinned in VGPRs via empty-asm fence so the
// compiler cannot rematerialize the loads inside the node loop (VGPR=60 remat
// was the r2/r4 failure). x-row made wave-uniform -> scalar loads.
__global__ __launch_bounds__(256) void k_xform(
    const float* __restrict__ x, const float* __restrict__ Wt,
    float* __restrict__ h, int n, int nwaves) {
    const int lane = threadIdx.x & 63;

    float4 wt[16];
    const float4* wrow = (const float4*)(Wt + (size_t)lane * D);
#pragma unroll
    for (int g = 0; g < 16; ++g) {
        wt[g] = wrow[g];
        // opacity fence: value must stay live in VGPRs, no remat of the load
        asm volatile("" : "+v"(wt[g].x), "+v"(wt[g].y), "+v"(wt[g].z), "+v"(wt[g].w));
    }

    const int w0 = blockIdx.x * 4 + (threadIdx.x >> 6);
    for (int w = w0; w < n; w += nwaves) {
        const int wu = __builtin_amdgcn_readfirstlane(w);   // uniform -> s_load
        const float4* xr = (const float4*)(x + (size_t)wu * D);
        float y = 0.f;
#pragma unroll
        for (int g = 0; g < 16; ++g) {
            float4 a = xr[g];
            y += a.x * wt[g].x + a.y * wt[g].y + a.z * wt[g].z + a.w * wt[g].w;
        }
        h[(size_t)wu * D + lane] = y;
    }
}

// ---------------- round kernel 2: CSR gather + bias + LayerNorm ----------------
// No W -> low VGPR -> high occupancy; deep unroll for loads-in-flight.
// Quarter q (lanes 16q..16q+15) owns edge slot q; lane loads float4 of the
// row: 4 edges per load instruction, 16 edges per iteration in flight.
__global__ __launch_bounds__(256) void k_gather(
    const float* __restrict__ h, const int* __restrict__ row_ptr,
    const int2* __restrict__ edge, const float* __restrict__ dis,
    const float* __restrict__ bb, const float* __restrict__ gamma,
    const float* __restrict__ beta, float* __restrict__ out, int n, int nwaves) {
    const int lane = threadIdx.x & 63;
    const int q    = lane >> 4;
    const int fl   = lane & 15;

    const float4 bv = ((const float4*)bb)[fl];
    const float4 gv = ((const float4*)gamma)[fl];
    const float4 ev = ((const float4*)beta)[fl];

    const int w0 = blockIdx.x * 4 + (threadIdx.x >> 6);
    for (int w = w0; w < n; w += nwaves) {
        const int jb = row_ptr[w], je = row_ptr[w + 1];
        float4 acc = make_float4(0.f, 0.f, 0.f, 0.f);
        int j = jb;
        for (; j + 16 <= je; j += 16) {          // 4 row loads in flight
            int2 e0 = edge[j + q];
            int2 e1 = edge[j + 4 + q];
            int2 e2 = edge[j + 8 + q];
            int2 e3 = edge[j + 12 + q];
            float4 v0 = ((const float4*)(h + (size_t)e0.x * D))[fl];
            float4 v1 = ((const float4*)(h + (size_t)e1.x * D))[fl];
            float4 v2 = ((const float4*)(h + (size_t)e2.x * D))[fl];
            float4 v3 = ((const float4*)(h + (size_t)e3.x * D))[fl];
            float w0_ = __int_as_float(e0.y), w1_ = __int_as_float(e1.y);
            float w2_ = __int_as_float(e2.y), w3_ = __int_as_float(e3.y);
            acc.x += w0_ * v0.x; acc.y += w0_ * v0.y; acc.z += w0_ * v0.z; acc.w += w0_ * v0.w;
            acc.x += w1_ * v1.x; acc.y += w1_ * v1.y; acc.z += w1_ * v1.z; acc.w += w1_ * v1.w;
            acc.x += w2_ * v2.x; acc.y += w2_ * v2.y; acc.z += w2_ * v2.z; acc.w += w2_ * v2.w;
            acc.x += w3_ * v3.x; acc.y += w3_ * v3.y; acc.z += w3_ * v3.z; acc.w += w3_ * v3.w;
        }
        if (j + 8 <= je) {
            int2 e0 = edge[j + q];
            int2 e1 = edge[j + 4 + q];
            float4 v0 = ((const float4*)(h + (size_t)e0.x * D))[fl];
            float4 v1 = ((const float4*)(h + (size_t)e1.x * D))[fl];
            float w0_ = __int_as_float(e0.y), w1_ = __int_as_float(e1.y);
            acc.x += w0_ * v0.x; acc.y += w0_ * v0.y; acc.z += w0_ * v0.z; acc.w += w0_ * v0.w;
            acc.x += w1_ * v1.x; acc.y += w1_ * v1.y; acc.z += w1_ * v1.z; acc.w += w1_ * v1.w;
            j += 8;
        }
        if (j + 4 <= je) {
            int2 e0 = edge[j + q];
            float4 v0 = ((const float4*)(h + (size_t)e0.x * D))[fl];
            float w0_ = __int_as_float(e0.y);
            acc.x += w0_ * v0.x; acc.y += w0_ * v0.y; acc.z += w0_ * v0.z; acc.w += w0_ * v0.w;
            j += 4;
        }
        if (j < je) {                            // 1..3 leftover: clamp + zero-weight
            int m = je - j;
            int2 e0 = edge[j + (q < m ? q : 0)];
            float w0_ = (q < m) ? __int_as_float(e0.y) : 0.f;
            float4 v0 = ((const float4*)(h + (size_t)e0.x * D))[fl];
            acc.x += w0_ * v0.x; acc.y += w0_ * v0.y; acc.z += w0_ * v0.z; acc.w += w0_ * v0.w;
        }
        // reduce partials across the 4 quarters (row replicated per quarter after)
        acc.x += __shfl_xor(acc.x, 16); acc.y += __shfl_xor(acc.y, 16);
        acc.z += __shfl_xor(acc.z, 16); acc.w += __shfl_xor(acc.w, 16);
        acc.x += __shfl_xor(acc.x, 32); acc.y += __shfl_xor(acc.y, 32);
        acc.z += __shfl_xor(acc.z, 32); acc.w += __shfl_xor(acc.w, 32);
        const float dv = dis[w];
        acc.x = acc.x * dv + bv.x; acc.y = acc.y * dv + bv.y;
        acc.z = acc.z * dv + bv.z; acc.w = acc.w * dv + bv.w;

        // LayerNorm: 16-lane reduction suffices (quarters hold identical copies)
        float s = acc.x + acc.y + acc.z + acc.w;
#pragma unroll
        for (int m = 1; m < 16; m <<= 1) s += __shfl_xor(s, m, 64);
        float mu = s * (1.0f / 64.0f);
        float dx = acc.x - mu, dy = acc.y - mu, dz = acc.z - mu, dw = acc.w - mu;
        float qv = dx * dx + dy * dy + dz * dz + dw * dw;
#pragma unroll
        for (int m = 1; m < 16; m <<= 1) qv += __shfl_xor(qv, m, 64);
        float rstd = rsqrtf(qv * (1.0f / 64.0f) + EPSV);
        if (q == 0) {
            float4 y;
            y.x = dx * rstd * gv.x + ev.x; y.y = dy * rstd * gv.y + ev.y;
            y.z = dz * rstd * gv.z + ev.z; y.w = dw * rstd * gv.w + ev.w;
            ((float4*)(out + (size_t)w * D))[fl] = y;
        }
    }
}

// ---------------- launch ----------------

extern "C" void kernel_launch(void* const* d_in, const int* in_sizes, int n_in,
                              void* d_out, int out_size, void* d_ws, size_t ws_size,
                              hipStream_t stream) {
    const float* x0    = (const float*)d_in[0];
    const int*   ei    = (const int*)d_in[1];
    const float* W     = (const float*)d_in[2];
    const float* b     = (const float*)d_in[3];
    const float* gamma = (const float*)d_in[4];
    const float* beta  = (const float*)d_in[5];

    const int N = in_sizes[0] / D;
    const int E = in_sizes[1] / 2;
    const int* src = ei;
    const int* dst = ei + E;

    char* ws = (char*)d_ws;
    size_t off = 0;
    auto alloc = [&](size_t bytes) {
        off = (off + 255) & ~(size_t)255;
        void* p = ws + off;
        off += bytes;
        return p;
    };
    int*   deg     = (int*)alloc((size_t)N * 4);
    int*   cursor  = (int*)alloc((size_t)N * 4);
    int*   incl    = (int*)alloc((size_t)N * 4);
    int*   bsums   = (int*)alloc(4096);
    int*   row_ptr = (int*)alloc((size_t)(N + 1) * 4);
    float* dis     = (float*)alloc((size_t)N * 4);
    int2*  edge    = (int2*)alloc((size_t)(E + N) * 8);
    float* Wt      = (float*)alloc((size_t)D * D * 4);
    float* t       = (float*)alloc((size_t)N * D * 4);   // ping-pong x
    float* h       = (float*)alloc((size_t)N * D * 4);   // transformed features
    (void)ws_size;

    const int nbN  = (N + 255) / 256;
    const int nbE  = (E + 255) / 256;
    const int nbEN = (E + N + 255) / 256;

    k_init<<<nbN, 256, 0, stream>>>(deg, cursor, N);
    k_count<<<nbE, 256, 0, stream>>>(dst, deg, E);
    k_scan_block<<<nbN, 256, 0, stream>>>(deg, incl, bsums, N);
    k_scan_sums<<<1, 1024, 0, stream>>>(bsums, nbN);
    k_finalize<<<nbN, 256, 0, stream>>>(incl, deg, bsums, row_ptr, dis, N, E + N);
    k_fill<<<nbEN, 256, 0, stream>>>(src, dst, row_ptr, cursor, dis, edge, E, N);
    k_transpose<<<1, 256, 0, stream>>>(W, Wt);

    float* out = (float*)d_out;
    const int GX = 1024;                   // xform: 4096 waves
    const int GG = 2048;                   // gather: 8192 waves
    const float* xin = x0;
    float* xs[4] = { t, out, t, out };     // final round lands in out
    for (int r = 0; r < 4; ++r) {
        k_xform <<<GX, 256, 0, stream>>>(xin, Wt, h, N, GX * 4);
        k_gather<<<GG, 256, 0, stream>>>(h, row_ptr, edge, dis, b, gamma, beta, xs[r], N, GG * 4);
        xin = xs[r];
    }
}